// Round 12
// baseline (412.124 us; speedup 1.0000x reference)
//
#include <hip/hip_runtime.h>
#include <hip/hip_bf16.h>

typedef __bf16 bf16x8 __attribute__((ext_vector_type(8)));
typedef float  f32x4  __attribute__((ext_vector_type(4)));

typedef __attribute__((address_space(1))) const void* as1p;
typedef __attribute__((address_space(3))) void*       as3p;

__device__ __forceinline__ void gl16(const void* g, void* l) {
    __builtin_amdgcn_global_load_lds((as1p)g, (as3p)l, 16, 0, 0);
}
#define MEMFENCE asm volatile("" ::: "memory")
#define BARRIER  do { MEMFENCE; __builtin_amdgcn_s_barrier(); MEMFENCE; } while (0)
#define LGKM0    asm volatile("s_waitcnt lgkmcnt(0)" ::: "memory")

// ---------------------------------------------------------------------------
// fp32 -> bf16 convert, 8 elements/thread, grid-stride
// ---------------------------------------------------------------------------
__global__ __launch_bounds__(256)
void cvt_f32_bf16(const float* __restrict__ in, __bf16* __restrict__ out, long n8)
{
    long i = (long)blockIdx.x * blockDim.x + threadIdx.x;
    const long stride = (long)gridDim.x * blockDim.x;
    for (; i < n8; i += stride) {
        f32x4 a = ((const f32x4*)in)[2*i];
        f32x4 b = ((const f32x4*)in)[2*i + 1];
        bf16x8 o;
        #pragma unroll
        for (int j = 0; j < 4; ++j) { o[j] = (__bf16)a[j]; o[4+j] = (__bf16)b[j]; }
        ((bf16x8*)out)[i] = o;
    }
}

__global__ __launch_bounds__(256)
void pack_bias(const float* __restrict__ a, const float* __restrict__ b,
               const float* __restrict__ c, float* __restrict__ o)
{
    int i = blockIdx.x * 256 + threadIdx.x;   // 3072 total
    const float* s = (i < 1024) ? a : (i < 2048) ? b : c;
    o[i] = s[i & 1023];
}

// ---------------------------------------------------------------------------
// fused pre-pass: cvt Wq|Wk|Wv -> wall (contiguous), cvt x -> xb, pack bias.
// ---------------------------------------------------------------------------
__global__ __launch_bounds__(256)
void prepass(const float* __restrict__ x,
             const float* __restrict__ Wq, const float* __restrict__ Wk,
             const float* __restrict__ Wv,
             const float* __restrict__ bq, const float* __restrict__ bk,
             const float* __restrict__ bv,
             __bf16* __restrict__ wall, __bf16* __restrict__ xb,
             float* __restrict__ bp)
{
    const long NW8 = 393216;     // 3 * 1048576 / 8
    const long NX8 = 2097152;    // 4 * 4194304 / 8
    long tid0 = (long)blockIdx.x * blockDim.x + threadIdx.x;
    if (tid0 < 3072) {
        const float* s = (tid0 < 1024) ? bq : (tid0 < 2048) ? bk : bv;
        bp[tid0] = s[tid0 & 1023];
    }
    const long stride = (long)gridDim.x * blockDim.x;
    for (long i = tid0; i < NW8 + NX8; i += stride) {
        const float* src;
        __bf16* dst;
        if (i < NW8) {
            int w = (int)(i >> 17);
            long off8 = i & 131071;
            src = ((w == 0) ? Wq : (w == 1) ? Wk : Wv) + off8 * 8;
            dst = wall + i * 8;
        } else {
            long j8 = i - NW8;
            src = x + j8 * 8;
            dst = xb + j8 * 8;
        }
        f32x4 a = ((const f32x4*)src)[0];
        f32x4 b = ((const f32x4*)src)[1];
        bf16x8 o;
        #pragma unroll
        for (int j = 0; j < 4; ++j) { o[j] = (__bf16)a[j]; o[4+j] = (__bf16)b[j]; }
        *(bf16x8*)dst = o;
    }
}

// ---------------------------------------------------------------------------
// 256x256-tile NT GEMM, BK=64, 8 waves (2Mx4N).
// LDS: A ring 3 x 32KB @0, B ring 2 x 32KB @98304 (160 KB total).
// Swizzle (involution on bits 4-6, row = byte>>7 within each 16KB half):
//   phys = logical ^ ((row & 7) << 4)  -> conflict-free wave64 ds_read_b128
//   (empirically 0 conflicts; do NOT deviate from this read pattern).
// SCHED 0 (free-flow, R10-proven): no intra-tile barriers; one counted
//   vmcnt + one barrier per K-tile. No setprio (R11: null).
// SCHED 1 (8-phase-v2): 4 double-barriered phases per K-tile, one
//   C-quadrant (16 MFMA) per phase, EXACTLY one half-tile (2 gl16) staged
//   per phase (m201 uniform-staging), lgkm0+setprio around MFMA clusters.
//   Same ring + counted-vmcnt(4) ledger as SCHED 0.
// NO XCD block swizzle: measured 3x FETCH blowup on the projection (R9).
// EPI 0: +bias[col], bf16 out (z = weight)   EPI 1: exp(acc*alpha) + row psums
// EPI 2: f32 out / rowsum                    EPI 3: split-K f32 partials
// ---------------------------------------------------------------------------
template<int EPI, int SCHED = 0>
__global__ __launch_bounds__(512, 2)
void gemm8p(const __bf16* __restrict__ A, const __bf16* __restrict__ B,
            void* __restrict__ C0, void* __restrict__ C1,
            const float* __restrict__ aux, float* __restrict__ psum,
            int ldA, int ldB, int ldC, int Ktiles,
            long szA, long szB, long szC, long szAux, long szPsum,
            int nkz, float alpha)
{
    __shared__ char lds[163840];

    const int tid  = threadIdx.x;
    const int wave = tid >> 6, lane = tid & 63;
    const int wm = wave >> 2, wn = wave & 3;          // 2 x 4 wave grid
    const int rl = lane & 15, kg = lane >> 4;
    const int z  = blockIdx.z;

    const __bf16* Ab = A + (long)z * ((EPI == 0) ? 0 : szA);
    const __bf16* Bb = B + (long)z * szB;

    // ---- staging: thread covers phys granules P=tid*16 and P+8192 per half.
    const int P     = tid * 16;
    const int srow  = P >> 7;                         // 0..63
    const int scolb = (P & 127) ^ ((srow & 7) << 4);  // byte col in 128B row
    const long rbA = (long)ldA * 2;
    const long rbB = (long)ldB * 2;
    const char* gA = (const char*)Ab + ((long)blockIdx.x * 256 + srow) * rbA + scolb;
    const char* gB = (const char*)Bb + ((long)blockIdx.y * 256 + srow) * rbB + scolb;

    auto stageA = [&](int buf, int h, int kt) {
        const char* s = gA + (long)h * 128 * rbA + (long)kt * 128;
        char* d = lds + buf * 32768 + h * 16384 + wave * 1024;
        gl16(s, d);
        gl16(s + 64 * rbA, d + 8192);
    };
    auto stageB = [&](int buf, int h, int kt) {
        const char* s = gB + (long)h * 128 * rbB + (long)kt * 128;
        char* d = lds + 98304 + buf * 32768 + h * 16384 + wave * 1024;
        gl16(s, d);
        gl16(s + 64 * rbB, d + 8192);
    };

    // ---- fragment reads: logical byte = row*128 + ks*64 + kg*16,
    // row = (mi|ni)*16 + rl (row&7 == rl&7)  ->  phys col XOR (rl&7)<<4.
    const int csw[2] = { (kg << 4) ^ ((rl & 7) << 4),
                         ((kg << 4) ^ ((rl & 7) << 4)) ^ 64 };
    const int aoff = wm * 16384 + rl * 128;                      // + mi*2048 + csw[ks]
    const int boff = (wn >> 1) * 16384 + ((wn & 1) * 64 + rl) * 128; // + ni*2048 + csw[ks]

    // ---- prologue: tile0 (A+B) and A(1); wait tile0 (A(1)'s 4 loads may fly)
    stageA(0, 0, 0); stageA(0, 1, 0);
    stageB(0, 0, 0); stageB(0, 1, 0);
    if (Ktiles > 1) {
        stageA(1, 0, 1); stageA(1, 1, 1);
        asm volatile("s_waitcnt vmcnt(4)" ::: "memory");
    } else {
        asm volatile("s_waitcnt vmcnt(0)" ::: "memory");
    }
    BARRIER;

    f32x4 acc[8][4] = {};
    int ab = 0, bb = 0, as_ = 2;       // t%3, t&1, (t+2)%3

    for (int t = 0; t < Ktiles; ++t) {
        const char* rA = lds + ab * 32768;
        const char* rB = lds + 98304 + bb * 32768;
        const int sbb = bb ^ 1;
        bf16x8 a[4][2], b[4][2];

        if constexpr (SCHED == 0) {
            // ---------------- free-flow (R10-proven) ----------------
            #pragma unroll
            for (int mi = 0; mi < 4; ++mi)
                #pragma unroll
                for (int ks = 0; ks < 2; ++ks)
                    a[mi][ks] = *(const bf16x8*)(rA + aoff + mi * 2048 + csw[ks]);
            #pragma unroll
            for (int ni = 0; ni < 4; ++ni)
                #pragma unroll
                for (int ks = 0; ks < 2; ++ks)
                    b[ni][ks] = *(const bf16x8*)(rB + boff + ni * 2048 + csw[ks]);
            if (t + 1 < Ktiles) { stageB(sbb, 0, t + 1); stageB(sbb, 1, t + 1); }

            #pragma unroll
            for (int mi = 0; mi < 4; ++mi)
                #pragma unroll
                for (int ni = 0; ni < 4; ++ni)
                    #pragma unroll
                    for (int ks = 0; ks < 2; ++ks)
                        acc[mi][ni] = __builtin_amdgcn_mfma_f32_16x16x32_bf16(
                            a[mi][ks], b[ni][ks], acc[mi][ni], 0, 0, 0);

            #pragma unroll
            for (int mi = 0; mi < 4; ++mi)
                #pragma unroll
                for (int ks = 0; ks < 2; ++ks)
                    a[mi][ks] = *(const bf16x8*)(rA + aoff + (4 + mi) * 2048 + csw[ks]);
            if (t + 2 < Ktiles) { stageA(as_, 0, t + 2); stageA(as_, 1, t + 2); }

            #pragma unroll
            for (int mi = 0; mi < 4; ++mi)
                #pragma unroll
                for (int ni = 0; ni < 4; ++ni)
                    #pragma unroll
                    for (int ks = 0; ks < 2; ++ks)
                        acc[4 + mi][ni] = __builtin_amdgcn_mfma_f32_16x16x32_bf16(
                            a[mi][ks], b[ni][ks], acc[4 + mi][ni], 0, 0, 0);

            if (t + 2 < Ktiles)      asm volatile("s_waitcnt vmcnt(4)" ::: "memory");
            else if (t + 1 < Ktiles) asm volatile("s_waitcnt vmcnt(0)" ::: "memory");
            if (t + 1 < Ktiles) BARRIER;
        } else {
            // ---------------- 8-phase-v2: uniform 1-half-tile/phase staging
            // ph1: read a[0-3], b[0-1]; stage B0(t+1)
            #pragma unroll
            for (int mi = 0; mi < 4; ++mi)
                #pragma unroll
                for (int ks = 0; ks < 2; ++ks)
                    a[mi][ks] = *(const bf16x8*)(rA + aoff + mi * 2048 + csw[ks]);
            #pragma unroll
            for (int ni = 0; ni < 2; ++ni)
                #pragma unroll
                for (int ks = 0; ks < 2; ++ks)
                    b[ni][ks] = *(const bf16x8*)(rB + boff + ni * 2048 + csw[ks]);
            if (t + 1 < Ktiles) stageB(sbb, 0, t + 1);
            BARRIER; LGKM0;
            __builtin_amdgcn_s_setprio(1);
            #pragma unroll
            for (int mi = 0; mi < 4; ++mi)
                #pragma unroll
                for (int ni = 0; ni < 2; ++ni)
                    #pragma unroll
                    for (int ks = 0; ks < 2; ++ks)
                        acc[mi][ni] = __builtin_amdgcn_mfma_f32_16x16x32_bf16(
                            a[mi][ks], b[ni][ks], acc[mi][ni], 0, 0, 0);
            __builtin_amdgcn_s_setprio(0);
            BARRIER;

            // ph2: read b[2-3]; stage B1(t+1)
            #pragma unroll
            for (int ni = 2; ni < 4; ++ni)
                #pragma unroll
                for (int ks = 0; ks < 2; ++ks)
                    b[ni][ks] = *(const bf16x8*)(rB + boff + ni * 2048 + csw[ks]);
            if (t + 1 < Ktiles) stageB(sbb, 1, t + 1);
            BARRIER; LGKM0;
            __builtin_amdgcn_s_setprio(1);
            #pragma unroll
            for (int mi = 0; mi < 4; ++mi)
                #pragma unroll
                for (int ni = 2; ni < 4; ++ni)
                    #pragma unroll
                    for (int ks = 0; ks < 2; ++ks)
                        acc[mi][ni] = __builtin_amdgcn_mfma_f32_16x16x32_bf16(
                            a[mi][ks], b[ni][ks], acc[mi][ni], 0, 0, 0);
            __builtin_amdgcn_s_setprio(0);
            BARRIER;

            // ph3: read a rows 4-7; stage A0(t+2)
            #pragma unroll
            for (int mi = 0; mi < 4; ++mi)
                #pragma unroll
                for (int ks = 0; ks < 2; ++ks)
                    a[mi][ks] = *(const bf16x8*)(rA + aoff + (4 + mi) * 2048 + csw[ks]);
            if (t + 2 < Ktiles) stageA(as_, 0, t + 2);
            BARRIER; LGKM0;
            __builtin_amdgcn_s_setprio(1);
            #pragma unroll
            for (int mi = 0; mi < 4; ++mi)
                #pragma unroll
                for (int ni = 0; ni < 2; ++ni)
                    #pragma unroll
                    for (int ks = 0; ks < 2; ++ks)
                        acc[4 + mi][ni] = __builtin_amdgcn_mfma_f32_16x16x32_bf16(
                            a[mi][ks], b[ni][ks], acc[4 + mi][ni], 0, 0, 0);
            __builtin_amdgcn_s_setprio(0);
            BARRIER;

            // ph4: stage A1(t+2); last quadrant; counted vmcnt
            if (t + 2 < Ktiles) stageA(as_, 1, t + 2);
            __builtin_amdgcn_s_setprio(1);
            #pragma unroll
            for (int mi = 0; mi < 4; ++mi)
                #pragma unroll
                for (int ni = 2; ni < 4; ++ni)
                    #pragma unroll
                    for (int ks = 0; ks < 2; ++ks)
                        acc[4 + mi][ni] = __builtin_amdgcn_mfma_f32_16x16x32_bf16(
                            a[mi][ks], b[ni][ks], acc[4 + mi][ni], 0, 0, 0);
            __builtin_amdgcn_s_setprio(0);
            if (t + 2 < Ktiles)      asm volatile("s_waitcnt vmcnt(4)" ::: "memory");
            else if (t + 1 < Ktiles) asm volatile("s_waitcnt vmcnt(0)" ::: "memory");
            if (t + 1 < Ktiles) BARRIER;
        }

        ab = (ab == 2) ? 0 : ab + 1;
        bb ^= 1;
        as_ = (as_ == 2) ? 0 : as_ + 1;
    }

    // ---- epilogue (C/D layout: row = (lane>>4)*4+j, col = lane&15)
    const int rowg = blockIdx.x * 256 + wm * 128 + kg * 4;
    const int colg = blockIdx.y * 256 + wn * 64 + rl;

    if (EPI == 0) {
        __bf16* C = (__bf16*)C0 + (long)z * szC;
        const float* bbv = aux + (long)z * szAux;
        float bv[4];
        #pragma unroll
        for (int ni = 0; ni < 4; ++ni) bv[ni] = bbv[colg + ni * 16];
        #pragma unroll
        for (int mi = 0; mi < 8; ++mi)
            #pragma unroll
            for (int j = 0; j < 4; ++j) {
                __bf16* cr = C + (long)(rowg + mi * 16 + j) * ldC + colg;
                #pragma unroll
                for (int ni = 0; ni < 4; ++ni)
                    cr[ni * 16] = (__bf16)(acc[mi][ni][j] + bv[ni]);
            }
    } else if (EPI == 1) {
        BARRIER;                               // LDS about to be reused (wsum)
        __bf16* C = (__bf16*)C0 + (long)z * szC;
        float* wsum = (float*)lds;
        float rsm[8][4];
        #pragma unroll
        for (int mi = 0; mi < 8; ++mi)
            #pragma unroll
            for (int j = 0; j < 4; ++j) {
                float s = 0.f;
                __bf16* cr = C + (long)(rowg + mi * 16 + j) * ldC + colg;
                #pragma unroll
                for (int ni = 0; ni < 4; ++ni) {
                    float e = __expf(acc[mi][ni][j] * alpha);
                    cr[ni * 16] = (__bf16)e;
                    s += e;
                }
                rsm[mi][j] = s;
            }
        #pragma unroll
        for (int mi = 0; mi < 8; ++mi)
            #pragma unroll
            for (int j = 0; j < 4; ++j) {
                float s = rsm[mi][j];
                s += __shfl_xor(s, 1); s += __shfl_xor(s, 2);
                s += __shfl_xor(s, 4); s += __shfl_xor(s, 8);
                rsm[mi][j] = s;
            }
        if (rl == 0) {
            #pragma unroll
            for (int mi = 0; mi < 8; ++mi)
                #pragma unroll
                for (int j = 0; j < 4; ++j)
                    wsum[wn * 256 + wm * 128 + mi * 16 + kg * 4 + j] = rsm[mi][j];
        }
        __syncthreads();
        if (tid < 256) {
            float s = wsum[tid] + wsum[256 + tid] + wsum[512 + tid] + wsum[768 + tid];
            psum[(long)z * szPsum + (long)blockIdx.y * 4096 + blockIdx.x * 256 + tid] = s;
        }
    } else if (EPI == 2) {
        float* C = (float*)C0 + (long)z * szC;
        const float* rs = aux + (long)z * szAux;
        #pragma unroll
        for (int mi = 0; mi < 8; ++mi)
            #pragma unroll
            for (int j = 0; j < 4; ++j) {
                int r = rowg + mi * 16 + j;
                float inv = 1.f / rs[r];
                float* cr = C + (long)r * ldC + colg;
                #pragma unroll
                for (int ni = 0; ni < 4; ++ni) cr[ni * 16] = acc[mi][ni][j] * inv;
            }
    } else {
        float* C = (z < nkz - 1) ? ((float*)C0 + (long)z * szC) : (float*)C1;
        #pragma unroll
        for (int mi = 0; mi < 8; ++mi)
            #pragma unroll
            for (int j = 0; j < 4; ++j) {
                float* cr = C + (long)(rowg + mi * 16 + j) * ldC + colg;
                #pragma unroll
                for (int ni = 0; ni < 4; ++ni) cr[ni * 16] = acc[mi][ni][j];
            }
    }
}

// ---------------------------------------------------------------------------
// bf16 transpose: in [T][D] -> out [D][T], 64x64 tiles via LDS
// ---------------------------------------------------------------------------
__global__ __launch_bounds__(256)
void transpose64(const __bf16* __restrict__ in, __bf16* __restrict__ out,
                 int T, int D, long sIn, long sOut)
{
    __shared__ __bf16 tile[64][72];
    const __bf16* pin  = in  + (long)blockIdx.z * sIn;
    __bf16*       pout = out + (long)blockIdx.z * sOut;
    const int t0 = blockIdx.x * 64, d0 = blockIdx.y * 64;
    const int tid = threadIdx.x;
    const int rr = tid >> 3;
    const int cc = (tid & 7) * 8;

    #pragma unroll
    for (int it = 0; it < 2; ++it) {
        int r = rr + it * 32;
        bf16x8 v = *(const bf16x8*)(pin + (long)(t0 + r) * D + d0 + cc);
        *(bf16x8*)&tile[r][cc] = v;
    }
    __syncthreads();
    #pragma unroll
    for (int it = 0; it < 2; ++it) {
        int dr = rr + it * 32;
        bf16x8 o;
        #pragma unroll
        for (int j = 0; j < 8; ++j) o[j] = tile[cc + j][dr];
        *(bf16x8*)(pout + (long)(d0 + dr) * T + t0 + cc) = o;
    }
}

// rs[b][r] = sum_{cb<16} psum[b][cb][r]
__global__ __launch_bounds__(256)
void rowsum16(const float* __restrict__ psum, float* __restrict__ rs)
{
    int i = blockIdx.x * 256 + threadIdx.x;
    int b = i >> 12, r = i & 4095;
    const float* p = psum + (long)b * 65536 + r;
    float s = 0.f;
    #pragma unroll
    for (int cb = 0; cb < 16; ++cb) s += p[cb * 4096];
    rs[i] = s;
}

// out = (out + sum parts) / rs[row]
__global__ __launch_bounds__(256)
void pv_reduce(float* __restrict__ outb, const float* __restrict__ parts,
               int np, const float* __restrict__ rs)
{
    long i = ((long)blockIdx.x * 256 + threadIdx.x) * 4;
    f32x4 v = *(f32x4*)(outb + i);
    for (int p = 0; p < np; ++p)
        v += *(const f32x4*)(parts + (long)p * 4194304 + i);
    float inv = 1.f / rs[i >> 10];
    v *= inv;
    *(f32x4*)(outb + i) = v;
}

// ---------------------------------------------------------------------------
extern "C" void kernel_launch(void* const* d_in, const int* in_sizes, int n_in,
                              void* d_out, int out_size, void* d_ws, size_t ws_size,
                              hipStream_t stream)
{
    const float* x  = (const float*)d_in[0];
    const float* Wq = (const float*)d_in[1];
    const float* bq = (const float*)d_in[2];
    const float* Wk = (const float*)d_in[3];
    const float* bk = (const float*)d_in[4];
    const float* Wv = (const float*)d_in[5];
    const float* bv = (const float*)d_in[6];
    float* out = (float*)d_out;

    const long T = 4096, E = 1024, D = 1024;
    const long TD = T * D;
    const long TT = T * T;
    const long WB = D * E;
    const float ALPHA = 1.0f / 32.0f;
    char* W = (char*)d_ws;

    const size_t need_A2 = 236007424;   // full-batch P via aggressive aliasing
    const size_t need_B2 = 191131648;

    if (ws_size >= need_A2) {
        __bf16* q    = (__bf16*)(W);
        __bf16* k    = (__bf16*)(W + 33554432);
        __bf16* vtmp = (__bf16*)(W + 67108864);
        __bf16* P    = (__bf16*)(W + 100663296);
        __bf16* xb   = (__bf16*)(W + 100663296);   // alias (dead before P write)
        __bf16* wall = (__bf16*)(W + 134217728);   // alias (dead before P write)
        __bf16* vt   = (__bf16*)(W);               // alias q (dead after QK^T)
        float*  psum = (float*) (W + 234881024);
        float*  rs   = (float*) (W + 235929600);
        float*  bp   = (float*) (W + 235995136);

        prepass<<<4096, 256, 0, stream>>>(x, Wq, Wk, Wv, bq, bk, bv, wall, xb, bp);

        // projections: SCHED=1 (8-phase-v2 A/B experiment)
        gemm8p<0, 1><<<dim3(64,4,3), 512, 0, stream>>>(
            xb, wall, q, nullptr, bp, nullptr,
            1024, 1024, 1024, 16, 0, WB, 4*TD, 1024, 0, 0, 0.f);

        // QK^T + exp + partial row sums (free-flow, proven)
        gemm8p<1, 0><<<dim3(16,16,4), 512, 0, stream>>>(
            q, k, P, nullptr, nullptr, psum,
            1024, 1024, 4096, 16, TD, TD, TT, 0, 65536, 0, ALPHA);

        // transpose V into q's space (q,k dead now)
        transpose64<<<dim3(64,16,4), 256, 0, stream>>>(vtmp, vt, (int)T, (int)D, TD, TD);

        rowsum16<<<64, 256, 0, stream>>>(psum, rs);

        // PV with fused rowsum divide (free-flow, proven)
        gemm8p<2, 0><<<dim3(16,4,4), 512, 0, stream>>>(
            P, vt, out, nullptr, rs, nullptr,
            4096, 4096, 1024, 64, TT, TD, TD, 4096, 0, 0, 0.f);
    } else if (ws_size >= need_B2) {
        __bf16* wall  = (__bf16*)(W);
        __bf16* xb    = (__bf16*)(W + 6291456);
        float*  parts = (float*) (W + 6291456);
        __bf16* vt    = (__bf16*)(W + 56623104);
        __bf16* q     = (__bf16*)(W + 90177536);
        __bf16* k     = (__bf16*)(W + 123731968);
        __bf16* P     = (__bf16*)(W + 157286400);
        float*  psum  = (float*) (W + 190840832);
        float*  rs    = (float*) (W + 191102976);
        float*  bp    = (float*) (W + 191119360);

        prepass<<<4096, 256, 0, stream>>>(x, Wq, Wk, Wv, bq, bk, bv, wall, xb, bp);

        gemm8p<0, 0><<<dim3(64,4,3), 512, 0, stream>>>(
            xb, wall, q, nullptr, bp, nullptr,
            1024, 1024, 1024, 16, 0, WB, 4*TD, 1024, 0, 0, 0.f);

        transpose64<<<dim3(64,16,4), 256, 0, stream>>>(P, vt, (int)T, (int)D, TD, TD);

        for (int b = 0; b < 4; ++b) {
            gemm8p<1, 0><<<dim3(16,16,1), 512, 0, stream>>>(
                q + b*TD, k + b*TD, P, nullptr, nullptr, psum,
                1024, 1024, 4096, 16, 0, 0, 0, 0, 0, 0, ALPHA);
            rowsum16<<<16, 256, 0, stream>>>(psum, rs);
            gemm8p<3, 0><<<dim3(16,4,4), 512, 0, stream>>>(
                P, vt + b*TD, parts, out + b*TD, nullptr, nullptr,
                4096, 4096, 1024, 16, 1024, 1024, TD, 0, 0, 4, 0.f);
            pv_reduce<<<4096, 256, 0, stream>>>(out + b*TD, parts, 3, rs);
        }
    } else {
        __bf16* wall  = (__bf16*)(W);
        __bf16* xb    = (__bf16*)(W + 6291456);
        float*  parts = (float*) (W + 6291456);
        __bf16* q     = (__bf16*)(W + 14680064);
        __bf16* k     = (__bf16*)(W + 23068672);
        __bf16* vt    = (__bf16*)(W + 31457280);
        __bf16* P     = (__bf16*)(W + 39845888);
        float*  psum  = (float*) (W + 73400320);
        float*  rs    = (float*) (W + 73662464);
        float*  bp    = (float*) (W + 73678848);

        pack_bias<<<12, 256, 0, stream>>>(bq, bk, bv, bp);
        cvt_f32_bf16<<<512, 256, 0, stream>>>(Wq, wall, WB/8);
        cvt_f32_bf16<<<512, 256, 0, stream>>>(Wk, wall + WB, WB/8);
        cvt_f32_bf16<<<512, 256, 0, stream>>>(Wv, wall + 2*WB, WB/8);

        for (int b = 0; b < 4; ++b) {
            cvt_f32_bf16<<<2048, 256, 0, stream>>>(x + b*TD, xb, TD/8);
            gemm8p<0, 0><<<dim3(16,4,1), 512, 0, stream>>>(
                xb, wall, q, nullptr, bp, nullptr,
                1024, 1024, 1024, 16, 0, 0, 0, 0, 0, 0, 0.f);
            gemm8p<0, 0><<<dim3(16,4,1), 512, 0, stream>>>(
                xb, wall + WB, k, nullptr, bp + 1024, nullptr,
                1024, 1024, 1024, 16, 0, 0, 0, 0, 0, 0, 0.f);
            gemm8p<0, 0><<<dim3(16,4,1), 512, 0, stream>>>(
                xb, wall + 2*WB, P, nullptr, bp + 2048, nullptr,
                1024, 1024, 1024, 16, 0, 0, 0, 0, 0, 0, 0.f);
            transpose64<<<dim3(64,16,1), 256, 0, stream>>>(P, vt, (int)T, (int)D, 0, 0);
            gemm8p<1, 0><<<dim3(16,16,1), 512, 0, stream>>>(
                q, k, P, nullptr, nullptr, psum,
                1024, 1024, 4096, 16, 0, 0, 0, 0, 0, 0, ALPHA);
            rowsum16<<<16, 256, 0, stream>>>(psum, rs);
            gemm8p<3, 0><<<dim3(16,4,2), 512, 0, stream>>>(
                P, vt, parts, out + b*TD, nullptr, nullptr,
                4096, 4096, 1024, 32, 2048, 2048, TD, 0, 0, 2, 0.f);
            pv_reduce<<<4096, 256, 0, stream>>>(out + b*TD, parts, 1, rs);
        }
    }
}

// Round 13
// 397.904 us; speedup vs baseline: 1.0357x; 1.0357x over previous
//
#include <hip/hip_runtime.h>
#include <hip/hip_bf16.h>

typedef __bf16 bf16x8 __attribute__((ext_vector_type(8)));
typedef float  f32x4  __attribute__((ext_vector_type(4)));

typedef __attribute__((address_space(1))) const void* as1p;
typedef __attribute__((address_space(3))) void*       as3p;

__device__ __forceinline__ void gl16(const void* g, void* l) {
    __builtin_amdgcn_global_load_lds((as1p)g, (as3p)l, 16, 0, 0);
}
#define MEMFENCE asm volatile("" ::: "memory")
#define BARRIER  do { MEMFENCE; __builtin_amdgcn_s_barrier(); MEMFENCE; } while (0)

// ---------------------------------------------------------------------------
// fp32 -> bf16 convert, 8 elements/thread, grid-stride
// ---------------------------------------------------------------------------
__global__ __launch_bounds__(256)
void cvt_f32_bf16(const float* __restrict__ in, __bf16* __restrict__ out, long n8)
{
    long i = (long)blockIdx.x * blockDim.x + threadIdx.x;
    const long stride = (long)gridDim.x * blockDim.x;
    for (; i < n8; i += stride) {
        f32x4 a = ((const f32x4*)in)[2*i];
        f32x4 b = ((const f32x4*)in)[2*i + 1];
        bf16x8 o;
        #pragma unroll
        for (int j = 0; j < 4; ++j) { o[j] = (__bf16)a[j]; o[4+j] = (__bf16)b[j]; }
        ((bf16x8*)out)[i] = o;
    }
}

__global__ __launch_bounds__(256)
void pack_bias(const float* __restrict__ a, const float* __restrict__ b,
               const float* __restrict__ c, float* __restrict__ o)
{
    int i = blockIdx.x * 256 + threadIdx.x;   // 3072 total
    const float* s = (i < 1024) ? a : (i < 2048) ? b : c;
    o[i] = s[i & 1023];
}

// ---------------------------------------------------------------------------
// fused pre-pass: cvt Wq|Wk|Wv -> wall (contiguous), cvt x -> xb, pack bias.
// ---------------------------------------------------------------------------
__global__ __launch_bounds__(256)
void prepass(const float* __restrict__ x,
             const float* __restrict__ Wq, const float* __restrict__ Wk,
             const float* __restrict__ Wv,
             const float* __restrict__ bq, const float* __restrict__ bk,
             const float* __restrict__ bv,
             __bf16* __restrict__ wall, __bf16* __restrict__ xb,
             float* __restrict__ bp)
{
    const long NW8 = 393216;     // 3 * 1048576 / 8
    const long NX8 = 2097152;    // 4 * 4194304 / 8
    long tid0 = (long)blockIdx.x * blockDim.x + threadIdx.x;
    if (tid0 < 3072) {
        const float* s = (tid0 < 1024) ? bq : (tid0 < 2048) ? bk : bv;
        bp[tid0] = s[tid0 & 1023];
    }
    const long stride = (long)gridDim.x * blockDim.x;
    for (long i = tid0; i < NW8 + NX8; i += stride) {
        const float* src;
        __bf16* dst;
        if (i < NW8) {
            int w = (int)(i >> 17);
            long off8 = i & 131071;
            src = ((w == 0) ? Wq : (w == 1) ? Wk : Wv) + off8 * 8;
            dst = wall + i * 8;
        } else {
            long j8 = i - NW8;
            src = x + j8 * 8;
            dst = xb + j8 * 8;
        }
        f32x4 a = ((const f32x4*)src)[0];
        f32x4 b = ((const f32x4*)src)[1];
        bf16x8 o;
        #pragma unroll
        for (int j = 0; j < 4; ++j) { o[j] = (__bf16)a[j]; o[4+j] = (__bf16)b[j]; }
        *(bf16x8*)dst = o;
    }
}

// ---------------------------------------------------------------------------
// 256x256-tile NT GEMM, BK=64, 8 waves (2Mx4N). [R10 — best measured, final]
// LDS: A ring 3 x 32KB @0, B ring 2 x 32KB @98304 (160 KB total).
// Swizzle (involution on bits 4-6, row = byte>>7 within each 16KB half):
//   phys = logical ^ ((row & 7) << 4)  -> conflict-free wave64 ds_read_b128
//   (empirically 0 conflicts; do NOT deviate from this read pattern).
// Free-flow schedule: no intra-tile barriers; one counted vmcnt + one
// barrier per K-tile (stage targets A(t+2)/B(t+1), safe for skew < 1 tile).
// Falsified alternatives (this session): intra-tile barriers (R3/R6/R12),
// 2-blocks/CU occupancy (R7), 32x32 MFMA (R8: 4-way conflicts), setprio
// (R11: null), XCD block swizzle (R9: 3x FETCH blowup).
// EPI 0: +bias[col], bf16 out (z = weight)   EPI 1: exp(acc*alpha) + row psums
// EPI 2: f32 out / rowsum                    EPI 3: split-K f32 partials
// ---------------------------------------------------------------------------
template<int EPI>
__global__ __launch_bounds__(512, 2)
void gemm8p(const __bf16* __restrict__ A, const __bf16* __restrict__ B,
            void* __restrict__ C0, void* __restrict__ C1,
            const float* __restrict__ aux, float* __restrict__ psum,
            int ldA, int ldB, int ldC, int Ktiles,
            long szA, long szB, long szC, long szAux, long szPsum,
            int nkz, float alpha)
{
    __shared__ char lds[163840];

    const int tid  = threadIdx.x;
    const int wave = tid >> 6, lane = tid & 63;
    const int wm = wave >> 2, wn = wave & 3;          // 2 x 4 wave grid
    const int rl = lane & 15, kg = lane >> 4;
    const int z  = blockIdx.z;

    const __bf16* Ab = A + (long)z * ((EPI == 0) ? 0 : szA);
    const __bf16* Bb = B + (long)z * szB;

    // ---- staging: thread covers phys granules P=tid*16 and P+8192 per half.
    const int P     = tid * 16;
    const int srow  = P >> 7;                         // 0..63
    const int scolb = (P & 127) ^ ((srow & 7) << 4);  // byte col in 128B row
    const long rbA = (long)ldA * 2;
    const long rbB = (long)ldB * 2;
    const char* gA = (const char*)Ab + ((long)blockIdx.x * 256 + srow) * rbA + scolb;
    const char* gB = (const char*)Bb + ((long)blockIdx.y * 256 + srow) * rbB + scolb;

    auto stageA = [&](int buf, int h, int kt) {
        const char* s = gA + (long)h * 128 * rbA + (long)kt * 128;
        char* d = lds + buf * 32768 + h * 16384 + wave * 1024;
        gl16(s, d);
        gl16(s + 64 * rbA, d + 8192);
    };
    auto stageB = [&](int buf, int h, int kt) {
        const char* s = gB + (long)h * 128 * rbB + (long)kt * 128;
        char* d = lds + 98304 + buf * 32768 + h * 16384 + wave * 1024;
        gl16(s, d);
        gl16(s + 64 * rbB, d + 8192);
    };

    // ---- fragment reads: logical byte = row*128 + ks*64 + kg*16,
    // row = (mi|ni)*16 + rl (row&7 == rl&7)  ->  phys col XOR (rl&7)<<4.
    const int csw[2] = { (kg << 4) ^ ((rl & 7) << 4),
                         ((kg << 4) ^ ((rl & 7) << 4)) ^ 64 };
    const int aoff = wm * 16384 + rl * 128;                      // + mi*2048 + csw[ks]
    const int boff = (wn >> 1) * 16384 + ((wn & 1) * 64 + rl) * 128; // + ni*2048 + csw[ks]

    // ---- prologue: tile0 (A+B) and A(1); wait tile0 (A(1)'s 4 loads may fly)
    stageA(0, 0, 0); stageA(0, 1, 0);
    stageB(0, 0, 0); stageB(0, 1, 0);
    if (Ktiles > 1) {
        stageA(1, 0, 1); stageA(1, 1, 1);
        asm volatile("s_waitcnt vmcnt(4)" ::: "memory");
    } else {
        asm volatile("s_waitcnt vmcnt(0)" ::: "memory");
    }
    BARRIER;

    f32x4 acc[8][4] = {};
    int ab = 0, bb = 0, as_ = 2;       // t%3, t&1, (t+2)%3

    for (int t = 0; t < Ktiles; ++t) {
        const char* rA = lds + ab * 32768;
        const char* rB = lds + 98304 + bb * 32768;
        const int sbb = bb ^ 1;
        bf16x8 a[4][2], b[4][2];

        // reads: A rows 0-3 + all B (16 b128); stage next-tile B
        #pragma unroll
        for (int mi = 0; mi < 4; ++mi)
            #pragma unroll
            for (int ks = 0; ks < 2; ++ks)
                a[mi][ks] = *(const bf16x8*)(rA + aoff + mi * 2048 + csw[ks]);
        #pragma unroll
        for (int ni = 0; ni < 4; ++ni)
            #pragma unroll
            for (int ks = 0; ks < 2; ++ks)
                b[ni][ks] = *(const bf16x8*)(rB + boff + ni * 2048 + csw[ks]);
        if (t + 1 < Ktiles) { stageB(sbb, 0, t + 1); stageB(sbb, 1, t + 1); }

        // MFMA upper half (acc rows 0-3)
        #pragma unroll
        for (int mi = 0; mi < 4; ++mi)
            #pragma unroll
            for (int ni = 0; ni < 4; ++ni)
                #pragma unroll
                for (int ks = 0; ks < 2; ++ks)
                    acc[mi][ni] = __builtin_amdgcn_mfma_f32_16x16x32_bf16(
                        a[mi][ks], b[ni][ks], acc[mi][ni], 0, 0, 0);

        // reads: A rows 4-7 (reuse a); stage A(t+2)
        #pragma unroll
        for (int mi = 0; mi < 4; ++mi)
            #pragma unroll
            for (int ks = 0; ks < 2; ++ks)
                a[mi][ks] = *(const bf16x8*)(rA + aoff + (4 + mi) * 2048 + csw[ks]);
        if (t + 2 < Ktiles) { stageA(as_, 0, t + 2); stageA(as_, 1, t + 2); }

        // MFMA lower half (acc rows 4-7)
        #pragma unroll
        for (int mi = 0; mi < 4; ++mi)
            #pragma unroll
            for (int ni = 0; ni < 4; ++ni)
                #pragma unroll
                for (int ks = 0; ks < 2; ++ks)
                    acc[4 + mi][ni] = __builtin_amdgcn_mfma_f32_16x16x32_bf16(
                        a[mi][ks], b[ni][ks], acc[4 + mi][ni], 0, 0, 0);

        // per-tile counted wait + single barrier (skip after last tile)
        if (t + 2 < Ktiles)      asm volatile("s_waitcnt vmcnt(4)" ::: "memory");
        else if (t + 1 < Ktiles) asm volatile("s_waitcnt vmcnt(0)" ::: "memory");
        if (t + 1 < Ktiles) BARRIER;

        ab = (ab == 2) ? 0 : ab + 1;
        bb ^= 1;
        as_ = (as_ == 2) ? 0 : as_ + 1;
    }

    // ---- epilogue (C/D layout: row = (lane>>4)*4+j, col = lane&15)
    const int rowg = blockIdx.x * 256 + wm * 128 + kg * 4;
    const int colg = blockIdx.y * 256 + wn * 64 + rl;

    if (EPI == 0) {
        __bf16* C = (__bf16*)C0 + (long)z * szC;
        const float* bbv = aux + (long)z * szAux;
        float bv[4];
        #pragma unroll
        for (int ni = 0; ni < 4; ++ni) bv[ni] = bbv[colg + ni * 16];
        #pragma unroll
        for (int mi = 0; mi < 8; ++mi)
            #pragma unroll
            for (int j = 0; j < 4; ++j) {
                __bf16* cr = C + (long)(rowg + mi * 16 + j) * ldC + colg;
                #pragma unroll
                for (int ni = 0; ni < 4; ++ni)
                    cr[ni * 16] = (__bf16)(acc[mi][ni][j] + bv[ni]);
            }
    } else if (EPI == 1) {
        BARRIER;                               // LDS about to be reused (wsum)
        __bf16* C = (__bf16*)C0 + (long)z * szC;
        float* wsum = (float*)lds;
        float rsm[8][4];
        #pragma unroll
        for (int mi = 0; mi < 8; ++mi)
            #pragma unroll
            for (int j = 0; j < 4; ++j) {
                float s = 0.f;
                __bf16* cr = C + (long)(rowg + mi * 16 + j) * ldC + colg;
                #pragma unroll
                for (int ni = 0; ni < 4; ++ni) {
                    float e = __expf(acc[mi][ni][j] * alpha);
                    cr[ni * 16] = (__bf16)e;
                    s += e;
                }
                rsm[mi][j] = s;
            }
        #pragma unroll
        for (int mi = 0; mi < 8; ++mi)
            #pragma unroll
            for (int j = 0; j < 4; ++j) {
                float s = rsm[mi][j];
                s += __shfl_xor(s, 1); s += __shfl_xor(s, 2);
                s += __shfl_xor(s, 4); s += __shfl_xor(s, 8);
                rsm[mi][j] = s;
            }
        if (rl == 0) {
            #pragma unroll
            for (int mi = 0; mi < 8; ++mi)
                #pragma unroll
                for (int j = 0; j < 4; ++j)
                    wsum[wn * 256 + wm * 128 + mi * 16 + kg * 4 + j] = rsm[mi][j];
        }
        __syncthreads();
        if (tid < 256) {
            float s = wsum[tid] + wsum[256 + tid] + wsum[512 + tid] + wsum[768 + tid];
            psum[(long)z * szPsum + (long)blockIdx.y * 4096 + blockIdx.x * 256 + tid] = s;
        }
    } else if (EPI == 2) {
        float* C = (float*)C0 + (long)z * szC;
        const float* rs = aux + (long)z * szAux;
        #pragma unroll
        for (int mi = 0; mi < 8; ++mi)
            #pragma unroll
            for (int j = 0; j < 4; ++j) {
                int r = rowg + mi * 16 + j;
                float inv = 1.f / rs[r];
                float* cr = C + (long)r * ldC + colg;
                #pragma unroll
                for (int ni = 0; ni < 4; ++ni) cr[ni * 16] = acc[mi][ni][j] * inv;
            }
    } else {
        float* C = (z < nkz - 1) ? ((float*)C0 + (long)z * szC) : (float*)C1;
        #pragma unroll
        for (int mi = 0; mi < 8; ++mi)
            #pragma unroll
            for (int j = 0; j < 4; ++j) {
                float* cr = C + (long)(rowg + mi * 16 + j) * ldC + colg;
                #pragma unroll
                for (int ni = 0; ni < 4; ++ni) cr[ni * 16] = acc[mi][ni][j];
            }
    }
}

// ---------------------------------------------------------------------------
// bf16 transpose: in [T][D] -> out [D][T], 64x64 tiles via LDS
// ---------------------------------------------------------------------------
__global__ __launch_bounds__(256)
void transpose64(const __bf16* __restrict__ in, __bf16* __restrict__ out,
                 int T, int D, long sIn, long sOut)
{
    __shared__ __bf16 tile[64][72];
    const __bf16* pin  = in  + (long)blockIdx.z * sIn;
    __bf16*       pout = out + (long)blockIdx.z * sOut;
    const int t0 = blockIdx.x * 64, d0 = blockIdx.y * 64;
    const int tid = threadIdx.x;
    const int rr = tid >> 3;
    const int cc = (tid & 7) * 8;

    #pragma unroll
    for (int it = 0; it < 2; ++it) {
        int r = rr + it * 32;
        bf16x8 v = *(const bf16x8*)(pin + (long)(t0 + r) * D + d0 + cc);
        *(bf16x8*)&tile[r][cc] = v;
    }
    __syncthreads();
    #pragma unroll
    for (int it = 0; it < 2; ++it) {
        int dr = rr + it * 32;
        bf16x8 o;
        #pragma unroll
        for (int j = 0; j < 8; ++j) o[j] = tile[cc + j][dr];
        *(bf16x8*)(pout + (long)(d0 + dr) * T + t0 + cc) = o;
    }
}

// rs[b][r] = sum_{cb<16} psum[b][cb][r]
__global__ __launch_bounds__(256)
void rowsum16(const float* __restrict__ psum, float* __restrict__ rs)
{
    int i = blockIdx.x * 256 + threadIdx.x;
    int b = i >> 12, r = i & 4095;
    const float* p = psum + (long)b * 65536 + r;
    float s = 0.f;
    #pragma unroll
    for (int cb = 0; cb < 16; ++cb) s += p[cb * 4096];
    rs[i] = s;
}

// out = (out + sum parts) / rs[row]
__global__ __launch_bounds__(256)
void pv_reduce(float* __restrict__ outb, const float* __restrict__ parts,
               int np, const float* __restrict__ rs)
{
    long i = ((long)blockIdx.x * 256 + threadIdx.x) * 4;
    f32x4 v = *(f32x4*)(outb + i);
    for (int p = 0; p < np; ++p)
        v += *(const f32x4*)(parts + (long)p * 4194304 + i);
    float inv = 1.f / rs[i >> 10];
    v *= inv;
    *(f32x4*)(outb + i) = v;
}

// ---------------------------------------------------------------------------
extern "C" void kernel_launch(void* const* d_in, const int* in_sizes, int n_in,
                              void* d_out, int out_size, void* d_ws, size_t ws_size,
                              hipStream_t stream)
{
    const float* x  = (const float*)d_in[0];
    const float* Wq = (const float*)d_in[1];
    const float* bq = (const float*)d_in[2];
    const float* Wk = (const float*)d_in[3];
    const float* bk = (const float*)d_in[4];
    const float* Wv = (const float*)d_in[5];
    const float* bv = (const float*)d_in[6];
    float* out = (float*)d_out;

    const long T = 4096, E = 1024, D = 1024;
    const long TD = T * D;
    const long TT = T * T;
    const long WB = D * E;
    const float ALPHA = 1.0f / 32.0f;
    char* W = (char*)d_ws;

    const size_t need_A2 = 236007424;   // full-batch P via aggressive aliasing
    const size_t need_B2 = 191131648;

    if (ws_size >= need_A2) {
        // Layout (aliased; order: prepass -> proj -> QK^T -> transpose -> PV):
        //  q     [0,   32MB)            (overwritten by vt after QK^T)
        //  k     [32,  64MB)
        //  vtmp  [64,  96MB)
        //  P     [96,  224MB)           (holds xb@96 + wall@128 during proj)
        //  psum  [224MB, +1MB)  rs  (+64KB)  bp (+12KB)
        __bf16* q    = (__bf16*)(W);
        __bf16* k    = (__bf16*)(W + 33554432);
        __bf16* vtmp = (__bf16*)(W + 67108864);
        __bf16* P    = (__bf16*)(W + 100663296);
        __bf16* xb   = (__bf16*)(W + 100663296);   // alias (dead before P write)
        __bf16* wall = (__bf16*)(W + 134217728);   // alias (dead before P write)
        __bf16* vt   = (__bf16*)(W);               // alias q (dead after QK^T)
        float*  psum = (float*) (W + 234881024);
        float*  rs   = (float*) (W + 235929600);
        float*  bp   = (float*) (W + 235995136);

        prepass<<<4096, 256, 0, stream>>>(x, Wq, Wk, Wv, bq, bk, bv, wall, xb, bp);

        // projections: q,k,vtmp contiguous at stride 32MB = 4*TD elems
        gemm8p<0><<<dim3(64,4,3), 512, 0, stream>>>(
            xb, wall, q, nullptr, bp, nullptr,
            1024, 1024, 1024, 16, 0, WB, 4*TD, 1024, 0, 0, 0.f);

        // QK^T + exp + partial row sums (clobbers xb/wall aliases — dead)
        gemm8p<1><<<dim3(16,16,4), 512, 0, stream>>>(
            q, k, P, nullptr, nullptr, psum,
            1024, 1024, 4096, 16, TD, TD, TT, 0, 65536, 0, ALPHA);

        // transpose V into q's space (q,k dead now)
        transpose64<<<dim3(64,16,4), 256, 0, stream>>>(vtmp, vt, (int)T, (int)D, TD, TD);

        rowsum16<<<64, 256, 0, stream>>>(psum, rs);

        // PV with fused rowsum divide
        gemm8p<2><<<dim3(16,4,4), 512, 0, stream>>>(
            P, vt, out, nullptr, rs, nullptr,
            4096, 4096, 1024, 64, TT, TD, TD, 4096, 0, 0, 0.f);
    } else if (ws_size >= need_B2) {
        __bf16* wall  = (__bf16*)(W);
        __bf16* xb    = (__bf16*)(W + 6291456);
        float*  parts = (float*) (W + 6291456);
        __bf16* vt    = (__bf16*)(W + 56623104);
        __bf16* q     = (__bf16*)(W + 90177536);
        __bf16* k     = (__bf16*)(W + 123731968);
        __bf16* P     = (__bf16*)(W + 157286400);
        float*  psum  = (float*) (W + 190840832);
        float*  rs    = (float*) (W + 191102976);
        float*  bp    = (float*) (W + 191119360);

        prepass<<<4096, 256, 0, stream>>>(x, Wq, Wk, Wv, bq, bk, bv, wall, xb, bp);

        gemm8p<0><<<dim3(64,4,3), 512, 0, stream>>>(
            xb, wall, q, nullptr, bp, nullptr,
            1024, 1024, 1024, 16, 0, WB, 4*TD, 1024, 0, 0, 0.f);

        transpose64<<<dim3(64,16,4), 256, 0, stream>>>(P, vt, (int)T, (int)D, TD, TD);

        for (int b = 0; b < 4; ++b) {
            gemm8p<1><<<dim3(16,16,1), 512, 0, stream>>>(
                q + b*TD, k + b*TD, P, nullptr, nullptr, psum,
                1024, 1024, 4096, 16, 0, 0, 0, 0, 0, 0, ALPHA);
            rowsum16<<<16, 256, 0, stream>>>(psum, rs);
            gemm8p<3><<<dim3(16,4,4), 512, 0, stream>>>(
                P, vt + b*TD, parts, out + b*TD, nullptr, nullptr,
                4096, 4096, 1024, 16, 1024, 1024, TD, 0, 0, 4, 0.f);
            pv_reduce<<<4096, 256, 0, stream>>>(out + b*TD, parts, 3, rs);
        }
    } else {
        __bf16* wall  = (__bf16*)(W);
        __bf16* xb    = (__bf16*)(W + 6291456);
        float*  parts = (float*) (W + 6291456);
        __bf16* q     = (__bf16*)(W + 14680064);
        __bf16* k     = (__bf16*)(W + 23068672);
        __bf16* vt    = (__bf16*)(W + 31457280);
        __bf16* P     = (__bf16*)(W + 39845888);
        float*  psum  = (float*) (W + 73400320);
        float*  rs    = (float*) (W + 73662464);
        float*  bp    = (float*) (W + 73678848);

        pack_bias<<<12, 256, 0, stream>>>(bq, bk, bv, bp);
        cvt_f32_bf16<<<512, 256, 0, stream>>>(Wq, wall, WB/8);
        cvt_f32_bf16<<<512, 256, 0, stream>>>(Wk, wall + WB, WB/8);
        cvt_f32_bf16<<<512, 256, 0, stream>>>(Wv, wall + 2*WB, WB/8);

        for (int b = 0; b < 4; ++b) {
            cvt_f32_bf16<<<2048, 256, 0, stream>>>(x + b*TD, xb, TD/8);
            gemm8p<0><<<dim3(16,4,1), 512, 0, stream>>>(
                xb, wall, q, nullptr, bp, nullptr,
                1024, 1024, 1024, 16, 0, 0, 0, 0, 0, 0, 0.f);
            gemm8p<0><<<dim3(16,4,1), 512, 0, stream>>>(
                xb, wall + WB, k, nullptr, bp + 1024, nullptr,
                1024, 1024, 1024, 16, 0, 0, 0, 0, 0, 0, 0.f);
            gemm8p<0><<<dim3(16,4,1), 512, 0, stream>>>(
                xb, wall + 2*WB, P, nullptr, bp + 2048, nullptr,
                1024, 1024, 1024, 16, 0, 0, 0, 0, 0, 0, 0.f);
            transpose64<<<dim3(64,16,1), 256, 0, stream>>>(P, vt, (int)T, (int)D, 0, 0);
            gemm8p<1><<<dim3(16,16,1), 512, 0, stream>>>(
                q, k, P, nullptr, nullptr, psum,
                1024, 1024, 4096, 16, 0, 0, 0, 0, 0, 0, ALPHA);
            rowsum16<<<16, 256, 0, stream>>>(psum, rs);
            gemm8p<3><<<dim3(16,4,2), 512, 0, stream>>>(
                P, vt, parts, out + b*TD, nullptr, nullptr,
                4096, 4096, 1024, 32, 2048, 2048, TD, 0, 0, 2, 0.f);
            pv_reduce<<<4096, 256, 0, stream>>>(out + b*TD, parts, 1, rs);
        }
    }
}